// Round 2
// baseline (571.375 us; speedup 1.0000x reference)
//
#include <hip/hip_runtime.h>

// CollisionChecker: B=128 batches, T=256 points, H=W=256, C=16.
// valid[b] = AND over t of (in_bounds(t) && !(sum_c amap[b,gi,gj,c] > 100))
//
// Reference output dtype is BOOL -> harness reads d_out as int32 (0/1).
// Latency/launch-bound: only ~2.5 MiB of memory traffic total.
// One block per batch, one thread per trajectory point.

#define BB 128
#define TT 256
#define HH 256
#define WW 256
#define CC 16

__global__ __launch_bounds__(256) void collision_kernel(
    const float* __restrict__ traj,   // (B, T, 2)
    const float* __restrict__ amap,   // (B, H, W, C)
    int* __restrict__ out)            // (B,) int32 0/1
{
    const int b = blockIdx.x;
    const int t = threadIdx.x;

    // Coalesced: consecutive threads read consecutive float2s.
    float2 pt = ((const float2*)traj)[(size_t)b * TT + t];

    // Match reference float32 op order exactly: ((pt + 10.0)/20.0 * scale)
    // then astype(int32) == C truncation (values are >= 0 here).
    float fx = (pt.x + 10.0f) / 20.0f * (float)HH;
    float fy = (pt.y + 10.0f) / 20.0f * (float)WW;
    int gi = (int)fx;
    int gj = (int)fy;

    bool in_bounds = (gi >= 0) && (gi < HH) && (gj >= 0) && (gj < WW);
    int gic = min(max(gi, 0), HH - 1);
    int gjc = min(max(gj, 0), WW - 1);

    // 64 contiguous bytes per gather, 16B-aligned: 4x float4.
    const float4* p = (const float4*)(amap +
        (((size_t)b * HH + (size_t)gic) * WW + (size_t)gjc) * CC);
    float4 a0 = p[0];
    float4 a1 = p[1];
    float4 a2 = p[2];
    float4 a3 = p[3];

    float mass = (a0.x + a0.y + a0.z + a0.w)
               + (a1.x + a1.y + a1.z + a1.w)
               + (a2.x + a2.y + a2.z + a2.w)
               + (a3.x + a3.y + a3.z + a3.w);

    // threshold is 25 sigma out for N(0,1) sums — summation order can't flip it
    bool ok = in_bounds && !(mass > 100.0f);

    __shared__ int flag;
    if (t == 0) flag = 1;
    __syncthreads();
    if (!ok) flag = 0;          // benign race: all writers store 0
    __syncthreads();
    if (t == 0) out[b] = flag;  // int32 0/1
}

extern "C" void kernel_launch(void* const* d_in, const int* in_sizes, int n_in,
                              void* d_out, int out_size, void* d_ws, size_t ws_size,
                              hipStream_t stream) {
    const float* traj = (const float*)d_in[0];   // (128, 256, 2) f32
    const float* amap = (const float*)d_in[1];   // (128, 256, 256, 16) f32
    int* out = (int*)d_out;                      // (128,) int32 (bool)

    collision_kernel<<<BB, TT, 0, stream>>>(traj, amap, out);
}